// Round 5
// baseline (369.323 us; speedup 1.0000x reference)
//
#include <hip/hip_runtime.h>
#include <cstdint>

// Problem constants (fixed by the reference setup)
#define BB   16      // batch
#define AA   16      // annotations per image
#define KK   80      // classes
#define NLEV 5       // pyramid levels (strides 8..128)
#define PP   21824   // total pyramid positions

#define POS_PER_BLK 256
#define NBLK_X ((PP + POS_PER_BLK - 1) / POS_PER_BLK)   // 86; blocks 0..84 full, block 85 has 64 pos
#define NBLK_TOT (NBLK_X * BB)                          // 1376

// ---------------- workspace layout (bytes) ----------------
//   0: float cls_sum[16] | 64: float reg_sum[16] | 128: int n_eff[16] | 192: uint done

// Projected-box bounds, identical arithmetic to the reference.
__device__ __forceinline__ void compute_bounds(const float* bx,
                                               float s, int* o, float* q)
{
#pragma clang fp contract(off)
    float p0 = floorf((bx[0] + s - 1.0f) / s);
    float p1 = floorf((bx[1] + s - 1.0f) / s);
    float p2 = floorf((bx[2] + s - 1.0f) / s);
    float p3 = floorf((bx[3] + s - 1.0f) / s);
    float pw = p2 - p0, ph = p3 - p1;
    float e0 = p0 + 0.4f * pw,  e1 = p1 + 0.4f * ph;
    float e2 = p2 - 0.4f * pw,  e3 = p3 - 0.4f * ph;
    float i0 = p0 + 0.25f * pw, i1 = p1 + 0.25f * ph;
    float i2 = p2 - 0.25f * pw, i3 = p3 - 0.25f * ph;
    o[0] = (int)floorf(e0);          // eff x >=
    o[1] = (int)floorf(e2 + 1.0f);   // eff x <=
    o[2] = (int)floorf(e1);          // eff y >=
    o[3] = (int)floorf(e3 + 1.0f);   // eff y <=
    o[4] = (int)floorf(i0 + 1.0f);   // ign x >=
    o[5] = (int)floorf(i2);          // ign x <=
    o[6] = (int)floorf(i1 + 1.0f);   // ign y >=
    o[7] = (int)floorf(i3);          // ign y <=
    q[0] = p0; q[1] = p1; q[2] = p2; q[3] = p3;
}

__device__ __forceinline__ float focal_term(float c, unsigned int em,
                                            unsigned int im, unsigned int cm)
{
    float cc  = fminf(fmaxf(c, 1e-4f), 1.0f - 1e-4f);
    bool  pos = (em & cm) != 0;
    bool  ign = (!pos) && ((im & cm) != 0);
    float arg = pos ? cc : (1.0f - cc);   // log argument
    float fwt = 1.0f - arg;               // == (pos ? 1-cc : cc)
    float af  = pos ? 0.25f : 0.75f;
    float l   = af * fwt * fwt * (-__logf(arg));
    return ign ? 0.0f : l;
}

// -------------------------------------------------------------------
// Single fused kernel; each block owns 256 consecutive positions of
// one image. Load ISSUE ORDER matches consumption order (ann -> grid/
// reg -> cls prefetch) so phase-0 waits leave the cls batch in flight.
// The last-finishing block (device-scope done counter) computes the
// final means -- no separate finalize launch.
// -------------------------------------------------------------------
__global__ void __launch_bounds__(256)
fused_kernel(const float4* __restrict__ cls4,     // B * (P*K/4)
             const float4* __restrict__ reg4,     // B*P
             const float* __restrict__ ann,       // B*A*5
             const int* __restrict__ xg, const int* __restrict__ yg,
             const int* __restrict__ lev,
             float* __restrict__ cls_sum, float* __restrict__ reg_sum,
             int* __restrict__ n_eff, unsigned int* __restrict__ done,
             float* __restrict__ out)
{
    __shared__ float sann[AA * 5];
    __shared__ int   sb[AA * NLEV * 8];
    __shared__ float sp[AA * NLEV * 4];
    __shared__ int   scid[AA];
    __shared__ uint4 scm[KK / 4];
    __shared__ unsigned int smask[POS_PER_BLK];
    __shared__ float swc[4], swr[4];
    __shared__ int   swn[4];
    __shared__ int   sdone;

    const int  b    = blockIdx.y;
    const int  t    = threadIdx.x;
    const int  p0   = blockIdx.x * POS_PER_BLK;
    const bool full = (blockIdx.x < NBLK_X - 1);
    const int  npos = full ? POS_PER_BLK : (PP - (NBLK_X - 1) * POS_PER_BLK); // 256 or 64

    // ---- issue 1: annotations (consumed first) ----
    const float* annb = ann + b * AA * 5;
    float av = 0.0f;
    if (t < AA * 5) av = annb[t];

    // ---- issue 2: grid + regression (consumed in phase 1) ----
    const int pc = p0 + ((t < npos) ? t : 0);
    int    x  = xg[pc], y = yg[pc], li = lev[pc];
    float4 r4 = reg4[(size_t)b * PP + pc];

    // ---- issue 3: cls prefetch batch 0 (consumed in phase 2) ----
    const int V = PP * KK / 4;
    const float4* cbase = cls4 + (size_t)b * V + (size_t)p0 * (KK / 4);
    float4 c0[10];
    if (full) {
#pragma unroll
        for (int u = 0; u < 10; ++u) c0[u] = cbase[t + 256 * u];
    } else {
#pragma unroll
        for (int u = 0; u < 5; ++u)  c0[u] = cbase[t + 256 * u];
    }

    if (t < AA * 5) sann[t] = av;
    __syncthreads();

    // ---- phase 0: bounds / class-membership masks from LDS ann ----
    if (t < AA * NLEV) {
        int l = t % NLEV, a = t / NLEV;
        compute_bounds(&sann[a * 5], (float)(8 << l), &sb[t * 8], &sp[t * 4]);
    }
    if (t >= 128 && t < 128 + KK) {
        int k = t - 128;
        unsigned int m = 0;
        for (int a = 0; a < AA; ++a)
            if ((int)sann[a * 5 + 4] == k) m |= (1u << a);
        ((unsigned int*)scm)[k] = m;
    }
    if (t >= 232 && t < 232 + AA) scid[t - 232] = (int)sann[(t - 232) * 5 + 4];
    __syncthreads();

    // ---- phase 1: position masks + IoU reg loss ----
    float my_r = 0.0f; int my_n = 0;
    if (t < npos) {
        unsigned int em = 0, im = 0;
        for (int a = 0; a < AA; ++a) {
            const int* o = &sb[(a * NLEV + li) * 8];
            int me = (x >= o[0]) & (x <= o[1]) & (y >= o[2]) & (y <= o[3]);
            int mi = (x >= o[4]) & (x <= o[5]) & (y >= o[6]) & (y <= o[7]);
            em |= (unsigned int)me << a;
            im |= (unsigned int)mi << a;
        }
        smask[t] = em | (im << 16);

        // distinct positive classes at this position
        unsigned long long lo = 0; unsigned int hi = 0;
        unsigned int m = em;
        while (m) {
            int a = __ffs(m) - 1; m &= m - 1;
            int c = scid[a];
            if (c < 64) lo |= 1ull << c; else hi |= 1u << (c - 64);
        }
        int np = __popcll(lo) + __popc(hi);

        // box of LAST covering annotation (default A-1 when none)
        int last = em ? (31 - __clz(em)) : (AA - 1);
        const float* pb = &sp[(last * NLEV + li) * 4];
        float xf = (float)x, yf = (float)y;
        float t0 = (xf - pb[0]) * 0.25f;
        float t1 = (pb[2] - xf) * 0.25f;
        float t2 = (yf - pb[1]) * 0.25f;
        float t3 = (pb[3] - yf) * 0.25f;
        float x_gt = (t2 + t3 + 1.0f) * (t0 + t1 + 1.0f);
        float x_pr = (r4.z + r4.w + 1.0f) * (r4.x + r4.y + 1.0f);
        float ih = fminf(t2, r4.z) + fminf(t3, r4.w) + 1.0f;
        float iw = fminf(t0, r4.x) + fminf(t1, r4.y) + 1.0f;
        float inter = ih * iw;
        float iou = inter / (x_pr + x_gt - inter);
        iou = fminf(fmaxf(iou, 1e-4f), 1.0f - 1e-4f);
        my_r = -logf(iou) * (float)np;
        my_n = np;
    }
    __syncthreads();

    // ---- phase 2: consume batch 0, overlap batch 1 (full blocks) ----
    float acc = 0.0f;
    if (full) {
        float4 c1[10];
#pragma unroll
        for (int u = 0; u < 10; ++u) c1[u] = cbase[t + 256 * (10 + u)];   // issue batch 1
#pragma unroll
        for (int u = 0; u < 10; ++u) {                                    // consume batch 0
            unsigned int il = (unsigned int)(t + 256 * u);
            unsigned int pl = il / 20u, k4 = il - pl * 20u;
            unsigned int mk = smask[pl];
            unsigned int em = mk & 0xFFFFu, im = mk >> 16;
            uint4 cm = scm[k4];
            acc += focal_term(c0[u].x, em, im, cm.x)
                 + focal_term(c0[u].y, em, im, cm.y)
                 + focal_term(c0[u].z, em, im, cm.z)
                 + focal_term(c0[u].w, em, im, cm.w);
        }
#pragma unroll
        for (int u = 0; u < 10; ++u) {                                    // consume batch 1
            unsigned int il = (unsigned int)(t + 256 * (10 + u));
            unsigned int pl = il / 20u, k4 = il - pl * 20u;
            unsigned int mk = smask[pl];
            unsigned int em = mk & 0xFFFFu, im = mk >> 16;
            uint4 cm = scm[k4];
            acc += focal_term(c1[u].x, em, im, cm.x)
                 + focal_term(c1[u].y, em, im, cm.y)
                 + focal_term(c1[u].z, em, im, cm.z)
                 + focal_term(c1[u].w, em, im, cm.w);
        }
    } else {
#pragma unroll
        for (int u = 0; u < 5; ++u) {
            unsigned int il = (unsigned int)(t + 256 * u);
            unsigned int pl = il / 20u, k4 = il - pl * 20u;
            unsigned int mk = smask[pl];
            unsigned int em = mk & 0xFFFFu, im = mk >> 16;
            uint4 cm = scm[k4];
            acc += focal_term(c0[u].x, em, im, cm.x)
                 + focal_term(c0[u].y, em, im, cm.y)
                 + focal_term(c0[u].z, em, im, cm.z)
                 + focal_term(c0[u].w, em, im, cm.w);
        }
    }

    // ---- epilogue: block reduce -> device atomics; last block finalizes ----
    for (int off = 32; off > 0; off >>= 1) {
        acc  += __shfl_down(acc,  off);
        my_r += __shfl_down(my_r, off);
        my_n += __shfl_down(my_n, off);
    }
    int lane = t & 63, wv = t >> 6;
    if (lane == 0) { swc[wv] = acc; swr[wv] = my_r; swn[wv] = my_n; }
    __syncthreads();
    if (t == 0) {
        atomicAdd(&cls_sum[b], swc[0] + swc[1] + swc[2] + swc[3]);
        atomicAdd(&reg_sum[b], swr[0] + swr[1] + swr[2] + swr[3]);
        atomicAdd(&n_eff[b],   swn[0] + swn[1] + swn[2] + swn[3]);
        __threadfence();
        unsigned int old = atomicAdd(done, 1u);
        sdone = (old == NBLK_TOT - 1) ? 1 : 0;
    }
    __syncthreads();

    if (sdone) {
        float c = 0.0f, r = 0.0f;
        if (t < BB) {
            __threadfence();
            // RMW readback -> coherent across XCDs
            float cs = atomicAdd(&cls_sum[t], 0.0f);
            float rs = atomicAdd(&reg_sum[t], 0.0f);
            int   n  = atomicAdd(&n_eff[t], 0);
            float d  = fmaxf((float)n, 1.0f);
            c = cs / d;
            r = (n > 0) ? (rs / d) : 0.0f;
        }
        for (int off = 32; off > 0; off >>= 1) {
            c += __shfl_down(c, off);
            r += __shfl_down(r, off);
        }
        if (t == 0) {
            out[0] = c * (1.0f / BB);
            out[1] = r * (1.0f / BB);
        }
    }
}

extern "C" void kernel_launch(void* const* d_in, const int* in_sizes, int n_in,
                              void* d_out, int out_size, void* d_ws, size_t ws_size,
                              hipStream_t stream)
{
    const float* cls = (const float*)d_in[0];
    const float* reg = (const float*)d_in[1];
    const float* ann = (const float*)d_in[2];
    // d_in[3] = image (unused)
    const int* xg = (const int*)d_in[4];
    const int* yg = (const int*)d_in[5];
    const int* lv = (const int*)d_in[6];
    float* out = (float*)d_out;

    char* ws = (char*)d_ws;
    float* cls_sum = (float*)(ws + 0);
    float* reg_sum = (float*)(ws + 64);
    int*   n_eff   = (int*)(ws + 128);
    unsigned int* done = (unsigned int*)(ws + 192);

    // zero accumulators + done counter (ws is poisoned 0xAA pre-launch)
    hipMemsetAsync(ws, 0, 256, stream);

    dim3 grid(NBLK_X, BB);
    fused_kernel<<<grid, 256, 0, stream>>>((const float4*)cls, (const float4*)reg,
                                           ann, xg, yg, lv,
                                           cls_sum, reg_sum, n_eff, done, out);
}

// Round 6
// 314.778 us; speedup vs baseline: 1.1733x; 1.1733x over previous
//
#include <hip/hip_runtime.h>
#include <cstdint>

// Problem constants (fixed by the reference setup)
#define BB   16      // batch
#define AA   16      // annotations per image
#define KK   80      // classes
#define NLEV 5       // pyramid levels (strides 8..128)
#define PP   21824   // total pyramid positions

#define POS_PER_BLK 256
#define NBLK_X ((PP + POS_PER_BLK - 1) / POS_PER_BLK)   // 86; blocks 0..84 full, block 85 has 64 pos

// ---------------- workspace layout (bytes) ----------------
// 0     : float pc[BB][NBLK_X]   per-block cls partial   (5504 B)
// 6144  : float pr[BB][NBLK_X]   per-block reg partial
// 12288 : int   pn[BB][NBLK_X]   per-block n_eff partial
// All slots are written unconditionally -> no zero-init, NO atomics.

// Projected-box bounds, identical arithmetic to the reference.
__device__ __forceinline__ void compute_bounds(const float* bx,
                                               float s, int* o, float* q)
{
#pragma clang fp contract(off)
    float p0 = floorf((bx[0] + s - 1.0f) / s);
    float p1 = floorf((bx[1] + s - 1.0f) / s);
    float p2 = floorf((bx[2] + s - 1.0f) / s);
    float p3 = floorf((bx[3] + s - 1.0f) / s);
    float pw = p2 - p0, ph = p3 - p1;
    float e0 = p0 + 0.4f * pw,  e1 = p1 + 0.4f * ph;
    float e2 = p2 - 0.4f * pw,  e3 = p3 - 0.4f * ph;
    float i0 = p0 + 0.25f * pw, i1 = p1 + 0.25f * ph;
    float i2 = p2 - 0.25f * pw, i3 = p3 - 0.25f * ph;
    o[0] = (int)floorf(e0);          // eff x >=
    o[1] = (int)floorf(e2 + 1.0f);   // eff x <=
    o[2] = (int)floorf(e1);          // eff y >=
    o[3] = (int)floorf(e3 + 1.0f);   // eff y <=
    o[4] = (int)floorf(i0 + 1.0f);   // ign x >=
    o[5] = (int)floorf(i2);          // ign x <=
    o[6] = (int)floorf(i1 + 1.0f);   // ign y >=
    o[7] = (int)floorf(i3);          // ign y <=
    q[0] = p0; q[1] = p1; q[2] = p2; q[3] = p3;
}

__device__ __forceinline__ float focal_term(float c, unsigned int em,
                                            unsigned int im, unsigned int cm)
{
    float cc  = fminf(fmaxf(c, 1e-4f), 1.0f - 1e-4f);
    bool  pos = (em & cm) != 0;
    bool  ign = (!pos) && ((im & cm) != 0);
    float arg = pos ? cc : (1.0f - cc);   // log argument
    float fwt = 1.0f - arg;               // == (pos ? 1-cc : cc)
    float af  = pos ? 0.25f : 0.75f;
    float l   = af * fwt * fwt * (-__logf(arg));
    return ign ? 0.0f : l;
}

// -------------------------------------------------------------------
// Fused kernel; each block owns 256 consecutive positions of one
// image. Epilogue is PLAIN STORES to per-block slots -- zero global
// atomic contention (the R5 profile showed per-line atomic
// serialization was ~100 us of the 132 us kernel).
// -------------------------------------------------------------------
__global__ void __launch_bounds__(256)
fused_kernel(const float4* __restrict__ cls4,     // B * (P*K/4)
             const float4* __restrict__ reg4,     // B*P
             const float* __restrict__ ann,       // B*A*5
             const int* __restrict__ xg, const int* __restrict__ yg,
             const int* __restrict__ lev,
             float* __restrict__ pc, float* __restrict__ pr,
             int* __restrict__ pn)
{
    __shared__ float sann[AA * 5];
    __shared__ int   sb[AA * NLEV * 8];
    __shared__ float sp[AA * NLEV * 4];
    __shared__ int   scid[AA];
    __shared__ uint4 scm[KK / 4];
    __shared__ unsigned int smask[POS_PER_BLK];
    __shared__ float swc[4], swr[4];
    __shared__ int   swn[4];

    const int  b    = blockIdx.y;
    const int  t    = threadIdx.x;
    const int  p0   = blockIdx.x * POS_PER_BLK;
    const bool full = (blockIdx.x < NBLK_X - 1);
    const int  npos = full ? POS_PER_BLK : (PP - (NBLK_X - 1) * POS_PER_BLK); // 256 or 64

    // ---- issue 1: annotations (consumed first) ----
    const float* annb = ann + b * AA * 5;
    float av = 0.0f;
    if (t < AA * 5) av = annb[t];

    // ---- issue 2: grid + regression (consumed in phase 1) ----
    const int pc_idx = p0 + ((t < npos) ? t : 0);
    int    x  = xg[pc_idx], y = yg[pc_idx], li = lev[pc_idx];
    float4 r4 = reg4[(size_t)b * PP + pc_idx];

    // ---- issue 3: cls prefetch batch 0 (consumed in phase 2) ----
    const int V = PP * KK / 4;
    const float4* cbase = cls4 + (size_t)b * V + (size_t)p0 * (KK / 4);
    float4 c0[10];
    if (full) {
#pragma unroll
        for (int u = 0; u < 10; ++u) c0[u] = cbase[t + 256 * u];
    } else {
#pragma unroll
        for (int u = 0; u < 5; ++u)  c0[u] = cbase[t + 256 * u];
    }

    if (t < AA * 5) sann[t] = av;
    __syncthreads();

    // ---- phase 0: bounds / class-membership masks from LDS ann ----
    if (t < AA * NLEV) {
        int l = t % NLEV, a = t / NLEV;
        compute_bounds(&sann[a * 5], (float)(8 << l), &sb[t * 8], &sp[t * 4]);
    }
    if (t >= 128 && t < 128 + KK) {
        int k = t - 128;
        unsigned int m = 0;
        for (int a = 0; a < AA; ++a)
            if ((int)sann[a * 5 + 4] == k) m |= (1u << a);
        ((unsigned int*)scm)[k] = m;
    }
    if (t >= 232 && t < 232 + AA) scid[t - 232] = (int)sann[(t - 232) * 5 + 4];
    __syncthreads();

    // ---- phase 1: position masks + IoU reg loss ----
    float my_r = 0.0f; int my_n = 0;
    if (t < npos) {
        unsigned int em = 0, im = 0;
        for (int a = 0; a < AA; ++a) {
            const int* o = &sb[(a * NLEV + li) * 8];
            int me = (x >= o[0]) & (x <= o[1]) & (y >= o[2]) & (y <= o[3]);
            int mi = (x >= o[4]) & (x <= o[5]) & (y >= o[6]) & (y <= o[7]);
            em |= (unsigned int)me << a;
            im |= (unsigned int)mi << a;
        }
        smask[t] = em | (im << 16);

        // distinct positive classes at this position
        unsigned long long lo = 0; unsigned int hi = 0;
        unsigned int m = em;
        while (m) {
            int a = __ffs(m) - 1; m &= m - 1;
            int c = scid[a];
            if (c < 64) lo |= 1ull << c; else hi |= 1u << (c - 64);
        }
        int np = __popcll(lo) + __popc(hi);

        // box of LAST covering annotation (default A-1 when none)
        int last = em ? (31 - __clz(em)) : (AA - 1);
        const float* pb = &sp[(last * NLEV + li) * 4];
        float xf = (float)x, yf = (float)y;
        float t0 = (xf - pb[0]) * 0.25f;
        float t1 = (pb[2] - xf) * 0.25f;
        float t2 = (yf - pb[1]) * 0.25f;
        float t3 = (pb[3] - yf) * 0.25f;
        float x_gt = (t2 + t3 + 1.0f) * (t0 + t1 + 1.0f);
        float x_pr = (r4.z + r4.w + 1.0f) * (r4.x + r4.y + 1.0f);
        float ih = fminf(t2, r4.z) + fminf(t3, r4.w) + 1.0f;
        float iw = fminf(t0, r4.x) + fminf(t1, r4.y) + 1.0f;
        float inter = ih * iw;
        float iou = inter / (x_pr + x_gt - inter);
        iou = fminf(fmaxf(iou, 1e-4f), 1.0f - 1e-4f);
        my_r = -logf(iou) * (float)np;
        my_n = np;
    }
    __syncthreads();

    // ---- phase 2: consume batch 0, overlap batch 1 (full blocks) ----
    float acc = 0.0f;
    if (full) {
        float4 c1[10];
#pragma unroll
        for (int u = 0; u < 10; ++u) c1[u] = cbase[t + 256 * (10 + u)];   // issue batch 1
#pragma unroll
        for (int u = 0; u < 10; ++u) {                                    // consume batch 0
            unsigned int il = (unsigned int)(t + 256 * u);
            unsigned int pl = il / 20u, k4 = il - pl * 20u;
            unsigned int mk = smask[pl];
            unsigned int em = mk & 0xFFFFu, im = mk >> 16;
            uint4 cm = scm[k4];
            acc += focal_term(c0[u].x, em, im, cm.x)
                 + focal_term(c0[u].y, em, im, cm.y)
                 + focal_term(c0[u].z, em, im, cm.z)
                 + focal_term(c0[u].w, em, im, cm.w);
        }
#pragma unroll
        for (int u = 0; u < 10; ++u) {                                    // consume batch 1
            unsigned int il = (unsigned int)(t + 256 * (10 + u));
            unsigned int pl = il / 20u, k4 = il - pl * 20u;
            unsigned int mk = smask[pl];
            unsigned int em = mk & 0xFFFFu, im = mk >> 16;
            uint4 cm = scm[k4];
            acc += focal_term(c1[u].x, em, im, cm.x)
                 + focal_term(c1[u].y, em, im, cm.y)
                 + focal_term(c1[u].z, em, im, cm.z)
                 + focal_term(c1[u].w, em, im, cm.w);
        }
    } else {
#pragma unroll
        for (int u = 0; u < 5; ++u) {
            unsigned int il = (unsigned int)(t + 256 * u);
            unsigned int pl = il / 20u, k4 = il - pl * 20u;
            unsigned int mk = smask[pl];
            unsigned int em = mk & 0xFFFFu, im = mk >> 16;
            uint4 cm = scm[k4];
            acc += focal_term(c0[u].x, em, im, cm.x)
                 + focal_term(c0[u].y, em, im, cm.y)
                 + focal_term(c0[u].z, em, im, cm.z)
                 + focal_term(c0[u].w, em, im, cm.w);
        }
    }

    // ---- epilogue: block reduce -> PLAIN store to distinct slot ----
    for (int off = 32; off > 0; off >>= 1) {
        acc  += __shfl_down(acc,  off);
        my_r += __shfl_down(my_r, off);
        my_n += __shfl_down(my_n, off);
    }
    int lane = t & 63, wv = t >> 6;
    if (lane == 0) { swc[wv] = acc; swr[wv] = my_r; swn[wv] = my_n; }
    __syncthreads();
    if (t == 0) {
        int slot = b * NBLK_X + blockIdx.x;
        pc[slot] = swc[0] + swc[1] + swc[2] + swc[3];
        pr[slot] = swr[0] + swr[1] + swr[2] + swr[3];
        pn[slot] = swn[0] + swn[1] + swn[2] + swn[3];
    }
}

// -------------------------------------------------------------------
// Final reduce: 16 images x 86 partials -> 2 outputs. One block.
// Thread t: image b = t/16, chunk = t%16 (16 lanes per image, so
// width-16 shuffles reduce within an image).
// -------------------------------------------------------------------
__global__ void final_kernel(const float* __restrict__ pc,
                             const float* __restrict__ pr,
                             const int* __restrict__ pn,
                             float* __restrict__ out)
{
    __shared__ float sc[BB], sr[BB];
    int t = threadIdx.x;          // 256
    int b = t >> 4, chunk = t & 15;
    float cs = 0.0f, rs = 0.0f; int ns = 0;
    for (int i = chunk; i < NBLK_X; i += 16) {
        cs += pc[b * NBLK_X + i];
        rs += pr[b * NBLK_X + i];
        ns += pn[b * NBLK_X + i];
    }
    for (int off = 8; off > 0; off >>= 1) {
        cs += __shfl_down(cs, off, 16);
        rs += __shfl_down(rs, off, 16);
        ns += __shfl_down(ns, off, 16);
    }
    if (chunk == 0) {
        float d = fmaxf((float)ns, 1.0f);
        sc[b] = cs / d;
        sr[b] = (ns > 0) ? (rs / d) : 0.0f;
    }
    __syncthreads();
    if (t == 0) {
        float C = 0.0f, R = 0.0f;
        for (int i = 0; i < BB; ++i) { C += sc[i]; R += sr[i]; }
        out[0] = C * (1.0f / BB);
        out[1] = R * (1.0f / BB);
    }
}

extern "C" void kernel_launch(void* const* d_in, const int* in_sizes, int n_in,
                              void* d_out, int out_size, void* d_ws, size_t ws_size,
                              hipStream_t stream)
{
    const float* cls = (const float*)d_in[0];
    const float* reg = (const float*)d_in[1];
    const float* ann = (const float*)d_in[2];
    // d_in[3] = image (unused)
    const int* xg = (const int*)d_in[4];
    const int* yg = (const int*)d_in[5];
    const int* lv = (const int*)d_in[6];
    float* out = (float*)d_out;

    char* ws = (char*)d_ws;
    float* pc = (float*)(ws + 0);
    float* pr = (float*)(ws + 6144);
    int*   pn = (int*)(ws + 12288);

    // No memset needed: every partial slot is written unconditionally.
    dim3 grid(NBLK_X, BB);
    fused_kernel<<<grid, 256, 0, stream>>>((const float4*)cls, (const float4*)reg,
                                           ann, xg, yg, lv, pc, pr, pn);

    final_kernel<<<1, 256, 0, stream>>>(pc, pr, pn, out);
}

// Round 7
// 312.212 us; speedup vs baseline: 1.1829x; 1.0082x over previous
//
#include <hip/hip_runtime.h>
#include <cstdint>

// Problem constants (fixed by the reference setup)
#define BB   16      // batch
#define AA   16      // annotations per image
#define KK   80      // classes
#define NLEV 5       // pyramid levels (strides 8..128)
#define PP   21824   // total pyramid positions

#define POS_PER_BLK 128
#define NBLK_X ((PP + POS_PER_BLK - 1) / POS_PER_BLK)   // 171; blocks 0..169 full, block 170 has 64 pos
// ---------------- workspace layout (bytes) ----------------
// 0     : float pc[BB][NBLK_X]   per-block cls partial  (10944 B)
// 12288 : float pr[BB][NBLK_X]
// 24576 : int   pn[BB][NBLK_X]
// All slots written unconditionally -> no zero-init, NO atomics.

// Projected-box bounds, identical arithmetic to the reference.
__device__ __forceinline__ void compute_bounds(float x1, float y1, float x2, float y2,
                                               float s, int* o, float* q)
{
#pragma clang fp contract(off)
    float p0 = floorf((x1 + s - 1.0f) / s);
    float p1 = floorf((y1 + s - 1.0f) / s);
    float p2 = floorf((x2 + s - 1.0f) / s);
    float p3 = floorf((y2 + s - 1.0f) / s);
    float pw = p2 - p0, ph = p3 - p1;
    float e0 = p0 + 0.4f * pw,  e1 = p1 + 0.4f * ph;
    float e2 = p2 - 0.4f * pw,  e3 = p3 - 0.4f * ph;
    float i0 = p0 + 0.25f * pw, i1 = p1 + 0.25f * ph;
    float i2 = p2 - 0.25f * pw, i3 = p3 - 0.25f * ph;
    o[0] = (int)floorf(e0);          // eff x >=
    o[1] = (int)floorf(e2 + 1.0f);   // eff x <=
    o[2] = (int)floorf(e1);          // eff y >=
    o[3] = (int)floorf(e3 + 1.0f);   // eff y <=
    o[4] = (int)floorf(i0 + 1.0f);   // ign x >=
    o[5] = (int)floorf(i2);          // ign x <=
    o[6] = (int)floorf(i1 + 1.0f);   // ign y >=
    o[7] = (int)floorf(i3);          // ign y <=
    q[0] = p0; q[1] = p1; q[2] = p2; q[3] = p3;
}

__device__ __forceinline__ float focal_term(float c, unsigned int em,
                                            unsigned int im, unsigned int cm)
{
    float cc  = fminf(fmaxf(c, 1e-4f), 1.0f - 1e-4f);
    bool  pos = (em & cm) != 0;
    bool  ign = (!pos) && ((im & cm) != 0);
    float arg = pos ? cc : (1.0f - cc);   // log argument
    float fwt = 1.0f - arg;               // == (pos ? 1-cc : cc)
    float af  = pos ? 0.25f : 0.75f;
    float l   = af * fwt * fwt * (-__logf(arg));
    return ign ? 0.0f : l;
}

// -------------------------------------------------------------------
// Fused kernel, 128 positions/block (2736 blocks for overlap).
// Load issue order = vmcnt FIFO order of consumption:
//   1) role-specific ann loads (phase-0 inputs, registers not LDS)
//   2) grid + regression (phase 1)
//   3) ALL of this thread's cls float4s (phase 2)
// Phase 0 computes from registers while the cls batch is in flight;
// only TWO barriers per block. Phase 2 is pure compute on registers.
// Epilogue: plain stores to distinct per-block slots (no atomics).
// -------------------------------------------------------------------
__global__ void __launch_bounds__(256)
fused_kernel(const float4* __restrict__ cls4,     // B * (P*K/4)
             const float4* __restrict__ reg4,     // B*P
             const float* __restrict__ ann,       // B*A*5
             const int* __restrict__ xg, const int* __restrict__ yg,
             const int* __restrict__ lev,
             float* __restrict__ pc, float* __restrict__ pr,
             int* __restrict__ pn)
{
    __shared__ int   sb[AA * NLEV * 8];
    __shared__ float sp[AA * NLEV * 4];
    __shared__ int   scid[AA];
    __shared__ uint4 scm[KK / 4];
    __shared__ unsigned int smask[POS_PER_BLK];
    __shared__ float swc[4], swr[4];
    __shared__ int   swn[4];

    const int  b    = blockIdx.y;
    const int  t    = threadIdx.x;
    const int  p0   = blockIdx.x * POS_PER_BLK;
    const bool full = (blockIdx.x < NBLK_X - 1);
    const int  npos = full ? POS_PER_BLK : (PP - (NBLK_X - 1) * POS_PER_BLK); // 128 or 64

    const float* annb = ann + b * AA * 5;

    // ---- issue 1: role-specific ann loads into REGISTERS ----
    float bx0 = 0, bx1 = 0, bx2 = 0, bx3 = 0, cid1 = 0;
    float cidv[AA];
    if (t < AA * NLEV) {                       // 80 bounds threads
        int a = t / NLEV;
        bx0 = annb[a * 5 + 0]; bx1 = annb[a * 5 + 1];
        bx2 = annb[a * 5 + 2]; bx3 = annb[a * 5 + 3];
    } else if (t >= 128 && t < 128 + KK) {     // 80 clsmask threads (16 shared addrs, L1 broadcast)
#pragma unroll
        for (int a = 0; a < AA; ++a) cidv[a] = annb[a * 5 + 4];
    } else if (t >= 224 && t < 224 + AA) {     // 16 scid threads
        cid1 = annb[(t - 224) * 5 + 4];
    }

    // ---- issue 2: grid + regression (consumed in phase 1) ----
    const int pidx = p0 + ((t < npos) ? t : 0);
    int    x  = xg[pidx], y = yg[pidx], li = lev[pidx];
    float4 r4 = reg4[(size_t)b * PP + pidx];

    // ---- issue 3: ALL cls float4s for this thread (consumed phase 2) ----
    const int V = PP * KK / 4;
    const float4* cbase = cls4 + (size_t)b * V + (size_t)p0 * (KK / 4);
    float4 c0[10];
    if (full) {
#pragma unroll
        for (int u = 0; u < 10; ++u) c0[u] = cbase[t + 256 * u];
    } else {
#pragma unroll
        for (int u = 0; u < 5; ++u)  c0[u] = cbase[t + 256 * u];
    }

    // ---- phase 0: compute from registers -> LDS (cls still in flight) ----
    if (t < AA * NLEV) {
        int l = t % NLEV;
        compute_bounds(bx0, bx1, bx2, bx3, (float)(8 << l), &sb[t * 8], &sp[t * 4]);
    } else if (t >= 128 && t < 128 + KK) {
        int k = t - 128;
        unsigned int m = 0;
#pragma unroll
        for (int a = 0; a < AA; ++a)
            if ((int)cidv[a] == k) m |= (1u << a);
        ((unsigned int*)scm)[k] = m;
    } else if (t >= 224 && t < 224 + AA) {
        scid[t - 224] = (int)cid1;
    }
    __syncthreads();   // B1

    // ---- phase 1: position masks + IoU reg loss ----
    float my_r = 0.0f; int my_n = 0;
    if (t < npos) {
        unsigned int em = 0, im = 0;
        for (int a = 0; a < AA; ++a) {
            const int* o = &sb[(a * NLEV + li) * 8];
            int me = (x >= o[0]) & (x <= o[1]) & (y >= o[2]) & (y <= o[3]);
            int mi = (x >= o[4]) & (x <= o[5]) & (y >= o[6]) & (y <= o[7]);
            em |= (unsigned int)me << a;
            im |= (unsigned int)mi << a;
        }
        smask[t] = em | (im << 16);

        // distinct positive classes at this position
        unsigned long long lo = 0; unsigned int hi = 0;
        unsigned int m = em;
        while (m) {
            int a = __ffs(m) - 1; m &= m - 1;
            int c = scid[a];
            if (c < 64) lo |= 1ull << c; else hi |= 1u << (c - 64);
        }
        int np = __popcll(lo) + __popc(hi);

        // box of LAST covering annotation (default A-1 when none)
        int last = em ? (31 - __clz(em)) : (AA - 1);
        const float* pb = &sp[(last * NLEV + li) * 4];
        float xf = (float)x, yf = (float)y;
        float t0 = (xf - pb[0]) * 0.25f;
        float t1 = (pb[2] - xf) * 0.25f;
        float t2 = (yf - pb[1]) * 0.25f;
        float t3 = (pb[3] - yf) * 0.25f;
        float x_gt = (t2 + t3 + 1.0f) * (t0 + t1 + 1.0f);
        float x_pr = (r4.z + r4.w + 1.0f) * (r4.x + r4.y + 1.0f);
        float ih = fminf(t2, r4.z) + fminf(t3, r4.w) + 1.0f;
        float iw = fminf(t0, r4.x) + fminf(t1, r4.y) + 1.0f;
        float inter = ih * iw;
        float iou = inter / (x_pr + x_gt - inter);
        iou = fminf(fmaxf(iou, 1e-4f), 1.0f - 1e-4f);
        my_r = -logf(iou) * (float)np;
        my_n = np;
    }
    __syncthreads();   // B2

    // ---- phase 2: pure compute on prefetched registers ----
    float acc = 0.0f;
    if (full) {
#pragma unroll
        for (int u = 0; u < 10; ++u) {
            unsigned int il = (unsigned int)(t + 256 * u);
            unsigned int pl = il / 20u, k4 = il - pl * 20u;
            unsigned int mk = smask[pl];
            unsigned int em = mk & 0xFFFFu, im = mk >> 16;
            uint4 cm = scm[k4];
            acc += focal_term(c0[u].x, em, im, cm.x)
                 + focal_term(c0[u].y, em, im, cm.y)
                 + focal_term(c0[u].z, em, im, cm.z)
                 + focal_term(c0[u].w, em, im, cm.w);
        }
    } else {
#pragma unroll
        for (int u = 0; u < 5; ++u) {
            unsigned int il = (unsigned int)(t + 256 * u);
            unsigned int pl = il / 20u, k4 = il - pl * 20u;
            unsigned int mk = smask[pl];
            unsigned int em = mk & 0xFFFFu, im = mk >> 16;
            uint4 cm = scm[k4];
            acc += focal_term(c0[u].x, em, im, cm.x)
                 + focal_term(c0[u].y, em, im, cm.y)
                 + focal_term(c0[u].z, em, im, cm.z)
                 + focal_term(c0[u].w, em, im, cm.w);
        }
    }

    // ---- epilogue: block reduce -> PLAIN store to distinct slot ----
    for (int off = 32; off > 0; off >>= 1) {
        acc  += __shfl_down(acc,  off);
        my_r += __shfl_down(my_r, off);
        my_n += __shfl_down(my_n, off);
    }
    int lane = t & 63, wv = t >> 6;
    if (lane == 0) { swc[wv] = acc; swr[wv] = my_r; swn[wv] = my_n; }
    __syncthreads();
    if (t == 0) {
        int slot = b * NBLK_X + blockIdx.x;
        pc[slot] = swc[0] + swc[1] + swc[2] + swc[3];
        pr[slot] = swr[0] + swr[1] + swr[2] + swr[3];
        pn[slot] = swn[0] + swn[1] + swn[2] + swn[3];
    }
}

// -------------------------------------------------------------------
// Final reduce: 16 images x 171 partials -> 2 outputs. One block.
// -------------------------------------------------------------------
__global__ void final_kernel(const float* __restrict__ pc,
                             const float* __restrict__ pr,
                             const int* __restrict__ pn,
                             float* __restrict__ out)
{
    __shared__ float sc[BB], sr[BB];
    int t = threadIdx.x;          // 256
    int b = t >> 4, chunk = t & 15;
    float cs = 0.0f, rs = 0.0f; int ns = 0;
    for (int i = chunk; i < NBLK_X; i += 16) {
        cs += pc[b * NBLK_X + i];
        rs += pr[b * NBLK_X + i];
        ns += pn[b * NBLK_X + i];
    }
    for (int off = 8; off > 0; off >>= 1) {
        cs += __shfl_down(cs, off, 16);
        rs += __shfl_down(rs, off, 16);
        ns += __shfl_down(ns, off, 16);
    }
    if (chunk == 0) {
        float d = fmaxf((float)ns, 1.0f);
        sc[b] = cs / d;
        sr[b] = (ns > 0) ? (rs / d) : 0.0f;
    }
    __syncthreads();
    if (t == 0) {
        float C = 0.0f, R = 0.0f;
        for (int i = 0; i < BB; ++i) { C += sc[i]; R += sr[i]; }
        out[0] = C * (1.0f / BB);
        out[1] = R * (1.0f / BB);
    }
}

extern "C" void kernel_launch(void* const* d_in, const int* in_sizes, int n_in,
                              void* d_out, int out_size, void* d_ws, size_t ws_size,
                              hipStream_t stream)
{
    const float* cls = (const float*)d_in[0];
    const float* reg = (const float*)d_in[1];
    const float* ann = (const float*)d_in[2];
    // d_in[3] = image (unused)
    const int* xg = (const int*)d_in[4];
    const int* yg = (const int*)d_in[5];
    const int* lv = (const int*)d_in[6];
    float* out = (float*)d_out;

    char* ws = (char*)d_ws;
    float* pc = (float*)(ws + 0);
    float* pr = (float*)(ws + 12288);
    int*   pn = (int*)(ws + 24576);

    // No memset needed: every partial slot is written unconditionally.
    dim3 grid(NBLK_X, BB);
    fused_kernel<<<grid, 256, 0, stream>>>((const float4*)cls, (const float4*)reg,
                                           ann, xg, yg, lv, pc, pr, pn);

    final_kernel<<<1, 256, 0, stream>>>(pc, pr, pn, out);
}